// Round 4
// baseline (402.035 us; speedup 1.0000x reference)
//
#include <hip/hip_runtime.h>
#include <math.h>

// Problem constants
#define NCOL 32768          // N = 32*32*32 columns
#define KAT  512            // dictionary atoms
#define DIM  64             // embedding dim
#define CPB  16             // columns per omp block (LDS 36 KB -> 4 blocks/CU)

// Output flat offsets (fp32 elements)
#define O_LOSS  0
#define O_RECON 1
#define O_ZF    2097153     // 1 + 2097152
#define O_PERP  4194305
#define O_GAMMA 4194306

// Workspace layout (fp32 elements)
#define WS_DN   0           // Dn  [64][512]
#define WS_DNT  32768       // DnT [512][64]
#define WS_G    65536       // G   [512][512]
#define WS_ACC  327680      // acc[0]=sum((recon-zf)^2), acc[1]=sum_n S_n

// ---------------------------------------------------------------------------
// DPP wave-64 reductions (all-VALU; result broadcast via readlane)
__device__ __forceinline__ float wave_max_bcast_f32(float v) {
    int x = __float_as_int(v);
    int t;
    t = __builtin_amdgcn_update_dpp(x, x, 0x111, 0xf, 0xf, false);  // row_shr:1
    x = __float_as_int(fmaxf(__int_as_float(x), __int_as_float(t)));
    t = __builtin_amdgcn_update_dpp(x, x, 0x112, 0xf, 0xf, false);  // row_shr:2
    x = __float_as_int(fmaxf(__int_as_float(x), __int_as_float(t)));
    t = __builtin_amdgcn_update_dpp(x, x, 0x114, 0xf, 0xf, false);  // row_shr:4
    x = __float_as_int(fmaxf(__int_as_float(x), __int_as_float(t)));
    t = __builtin_amdgcn_update_dpp(x, x, 0x118, 0xf, 0xf, false);  // row_shr:8
    x = __float_as_int(fmaxf(__int_as_float(x), __int_as_float(t)));
    t = __builtin_amdgcn_update_dpp(x, x, 0x142, 0xa, 0xf, false);  // row_bcast:15
    x = __float_as_int(fmaxf(__int_as_float(x), __int_as_float(t)));
    t = __builtin_amdgcn_update_dpp(x, x, 0x143, 0xc, 0xf, false);  // row_bcast:31
    x = __float_as_int(fmaxf(__int_as_float(x), __int_as_float(t)));
    return __int_as_float(__builtin_amdgcn_readlane(x, 63));
}

__device__ __forceinline__ unsigned wave_min_bcast_u32(unsigned v) {
    int x = (int)v;
    int t;
    t = __builtin_amdgcn_update_dpp(x, x, 0x111, 0xf, 0xf, false);
    x = (int)min((unsigned)x, (unsigned)t);
    t = __builtin_amdgcn_update_dpp(x, x, 0x112, 0xf, 0xf, false);
    x = (int)min((unsigned)x, (unsigned)t);
    t = __builtin_amdgcn_update_dpp(x, x, 0x114, 0xf, 0xf, false);
    x = (int)min((unsigned)x, (unsigned)t);
    t = __builtin_amdgcn_update_dpp(x, x, 0x118, 0xf, 0xf, false);
    x = (int)min((unsigned)x, (unsigned)t);
    t = __builtin_amdgcn_update_dpp(x, x, 0x142, 0xa, 0xf, false);
    x = (int)min((unsigned)x, (unsigned)t);
    t = __builtin_amdgcn_update_dpp(x, x, 0x143, 0xc, 0xf, false);
    x = (int)min((unsigned)x, (unsigned)t);
    return (unsigned)__builtin_amdgcn_readlane(x, 63);
}

// Full-wave sum, result broadcast via readlane.
__device__ __forceinline__ float wave_sum_bcast_f32(float v) {
    int x = __float_as_int(v);
    int t;
    t = __builtin_amdgcn_update_dpp(x, x, 0x0B1, 0xf, 0xf, false);  // quad_perm [1,0,3,2]
    x = __float_as_int(__int_as_float(x) + __int_as_float(t));
    t = __builtin_amdgcn_update_dpp(x, x, 0x04E, 0xf, 0xf, false);  // quad_perm [2,3,0,1]
    x = __float_as_int(__int_as_float(x) + __int_as_float(t));
    t = __builtin_amdgcn_update_dpp(x, x, 0x141, 0xf, 0xf, false);  // row_half_mirror
    x = __float_as_int(__int_as_float(x) + __int_as_float(t));
    t = __builtin_amdgcn_update_dpp(x, x, 0x140, 0xf, 0xf, false);  // row_mirror
    x = __float_as_int(__int_as_float(x) + __int_as_float(t));
    t = __builtin_amdgcn_update_dpp(x, x, 0x142, 0xa, 0xf, false);  // row_bcast:15
    x = __float_as_int(__int_as_float(x) + __int_as_float(t));
    t = __builtin_amdgcn_update_dpp(x, x, 0x143, 0xc, 0xf, false);  // row_bcast:31
    x = __float_as_int(__int_as_float(x) + __int_as_float(t));
    return __int_as_float(__builtin_amdgcn_readlane(x, 63));
}

// Sum over each 8-lane group, result on ALL lanes of the group (3 DPP stages).
__device__ __forceinline__ float sum8_all_f32(float v) {
    int x = __float_as_int(v);
    int t;
    t = __builtin_amdgcn_update_dpp(x, x, 0x0B1, 0xf, 0xf, false);  // xor1
    x = __float_as_int(__int_as_float(x) + __int_as_float(t));
    t = __builtin_amdgcn_update_dpp(x, x, 0x04E, 0xf, 0xf, false);  // xor2
    x = __float_as_int(__int_as_float(x) + __int_as_float(t));
    t = __builtin_amdgcn_update_dpp(x, x, 0x141, 0xf, 0xf, false);  // xor4 (half_mirror)
    x = __float_as_int(__int_as_float(x) + __int_as_float(t));
    return __int_as_float(x);
}

// ---------------------------------------------------------------------------
// Kernel 1: merged zf permutation-gather (blocks 0..1023) + gamma zero-fill
// (blocks 1024..9215) + dictionary prep (blocks 9216..9217).
__global__ __launch_bounds__(256) void zgp_kernel(const float* __restrict__ z_e,
                                                  const float* __restrict__ dict,
                                                  float* __restrict__ out,
                                                  float* __restrict__ ws) {
    __shared__ float tile[64 * 33];   // [c][w], pad to 33 -> conflict-free
    int t = threadIdx.x;
    if (blockIdx.x < 1024) {
        int s = blockIdx.x;           // one (b,h) slab each
        int b = s >> 5, h = s & 31;
        int srcbase = b * 65536 + h * 32;
        #pragma unroll
        for (int i = 0; i < 8; ++i) {
            int e = t + i * 256;      // e = c*32 + w
            int c = e >> 5, w = e & 31;
            tile[c * 33 + w] = z_e[srcbase + c * 1024 + w];
        }
        __syncthreads();
        int obase = O_ZF + s * 2048;
        #pragma unroll
        for (int i = 0; i < 8; ++i) {
            int e = t + i * 256;      // e = w*64 + c
            out[obase + e] = tile[(e & 63) * 33 + (e >> 6)];
        }
    } else if (blockIdx.x < 9216) {
        float2* g2 = (float2*)(out + O_GAMMA);   // region only 8B-aligned
        int id = (blockIdx.x - 1024) * 256 + t;  // 8192 blocks' worth
        #pragma unroll
        for (int i = 0; i < 4; ++i)
            g2[id + i * 2097152] = make_float2(0.f, 0.f);
    } else {
        // dictionary prep: normalize columns -> Dn, DnT; zero accumulators
        float* Dn  = ws + WS_DN;
        float* DnT = ws + WS_DNT;
        float* acc = ws + WS_ACC;
        int a = (blockIdx.x - 9216) * 256 + t;   // 0..511
        if (blockIdx.x == 9216 && t < 2) acc[t] = 0.f;
        float s = 0.f;
        #pragma unroll
        for (int d = 0; d < DIM; ++d) { float v = dict[d*KAT + a]; s += v * v; }
        float nrm = sqrtf(s);
        #pragma unroll
        for (int d = 0; d < DIM; ++d) {
            float v = dict[d*KAT + a] / nrm;
            Dn[d*KAT + a]  = v;
            DnT[a*DIM + d] = v;
        }
    }
}

// ---------------------------------------------------------------------------
// Kernel 2: G = Dn^T Dn.  block = row i (512 blocks), thread = col j (512).
// NOTE: G must be bit-symmetric (the omp kernel's Cholesky identity relies on
// it): fmaf(Dn_i, Dn_j, s) with operand swap is bit-identical, so it is.
__global__ void gram_kernel(const float* __restrict__ ws_in, float* __restrict__ ws) {
    const float* Dn = ws_in + WS_DN;
    float* G = ws + WS_G;
    int i = blockIdx.x, j = threadIdx.x;
    float s = 0.f;
    #pragma unroll
    for (int d = 0; d < DIM; ++d)
        s = fmaf(Dn[d*KAT + i], Dn[d*KAT + j], s);
    G[i*KAT + j] = s;
}

// ---------------------------------------------------------------------------
// Kernel 3: fused h_bar + Batch-OMP. 16 columns per 256-thread block; one wave
// per column, 4 columns/wave.
//
// Key change this round: the per-pick replicated Cholesky extension
// (7 uniform G loads at ~200cy L2 latency + ~28-deep dependent FMA chain)
// is replaced by the EXACT Batch-OMP identity  L[k][i] = u_i[idx_k]  — the
// idx_k-th component of the u-vectors already held in uv[] registers.
// (w = L^{-1} g, g[i] = G[Iv[i]][idx_k]; u_i = row i of L^{-1} G_I. Bit-exact
// vs the old chain by induction: identical fmaf sequence, G bit-symmetric.)
// Extraction is 8 cndmask + 1 readlane per entry: flat ops, no memory.
__global__ __launch_bounds__(256, 4) void omp_kernel(const float* __restrict__ z_e,
                                                     const float* __restrict__ ws,
                                                     float* __restrict__ out,
                                                     float* __restrict__ wsw) {
    const float* Dn  = ws + WS_DN;
    const float* DnT = ws + WS_DNT;
    const float* G   = ws + WS_G;
    float* acc = wsw + WS_ACC;

    __shared__ __align__(16) float xcols[DIM * CPB];  // [d][c]   4 KB
    __shared__ float hbar[CPB * KAT];                 // [c][a]  32 KB

    const int t = threadIdx.x;
    const int n_base = blockIdx.x * CPB;

    // ---- Phase 1: gather data columns
    #pragma unroll
    for (int i = 0; i < 4; ++i) {
        int e = t + i * 256;              // 0..1023, e = d*16 + c
        int d = e >> 4, c = e & 15;
        int L = d * NCOL + n_base + c;
        int src = (L >> 16) * 65536 + (L & 63) * 1024 + (((L >> 11) & 31) << 5) + ((L >> 6) & 31);
        xcols[e] = z_e[src];
    }
    __syncthreads();

    // ---- Phase 2: h_bar tile. Thread t handles atoms 2t,2t+1 via one float2
    // load per d (64 VMEM issues instead of 128; bit-exact per-atom math).
    {
        float a0[16], a1[16];
        #pragma unroll
        for (int i = 0; i < 16; ++i) { a0[i] = 0.f; a1[i] = 0.f; }
        const float2* Dn2 = (const float2*)Dn;
        const float4* xc4 = (const float4*)xcols;
        for (int d = 0; d < DIM; ++d) {
            float2 v = Dn2[d * 256 + t];
            #pragma unroll
            for (int q = 0; q < 4; ++q) {
                float4 xv = xc4[d * 4 + q];
                a0[q*4+0] = fmaf(v.x, xv.x, a0[q*4+0]);
                a0[q*4+1] = fmaf(v.x, xv.y, a0[q*4+1]);
                a0[q*4+2] = fmaf(v.x, xv.z, a0[q*4+2]);
                a0[q*4+3] = fmaf(v.x, xv.w, a0[q*4+3]);
                a1[q*4+0] = fmaf(v.y, xv.x, a1[q*4+0]);
                a1[q*4+1] = fmaf(v.y, xv.y, a1[q*4+1]);
                a1[q*4+2] = fmaf(v.y, xv.z, a1[q*4+2]);
                a1[q*4+3] = fmaf(v.y, xv.w, a1[q*4+3]);
            }
        }
        float2* hb2 = (float2*)hbar;
        #pragma unroll
        for (int c = 0; c < 16; ++c)
            hb2[c * 256 + t] = make_float2(a0[c], a1[c]);   // ds_write_b64, 2-way free
    }
    __syncthreads();

    // ---- Phase 3: OMP, one wave per column, 4 columns sequentially
    const int wv = t >> 6, lane = t & 63;
    float wv_sq = 0.f, wv_S = 0.f;

    #pragma unroll 1
    for (int cc = 0; cc < 4; ++cc) {
        const int col = wv * 4 + cc;
        const int n = n_base + col;
        const float* hbcol = hbar + col * KAT;

        float h[8];
        #pragma unroll
        for (int r = 0; r < 8; ++r) h[r] = hbcol[(r << 6) + lane];

        unsigned msk = 0;
        float uv[56];                 // u_0..u_6, uv[j*8+r]
        float Lr[28];                 // off-diag rows 1..7: Lr[i*(i-1)/2+j], j<i
        float invd[8], yv[8], xr[8];
        int Iv[8];

        #pragma unroll
        for (int k = 0; k < 8; ++k) {
            // local argmax over this lane's 8 slots — tree form (depth 3, not 8).
            // Tie semantics: strict '>' toward higher index keeps the LOWEST
            // index on exact ties, matching the sequential scan.
            float tv[8]; int ti[8]; float th[8];
            #pragma unroll
            for (int r = 0; r < 8; ++r) {
                tv[r] = ((msk >> r) & 1) ? -1.f : fabsf(h[r]);
                ti[r] = r;
                th[r] = h[r];
            }
            #pragma unroll
            for (int s = 1; s < 8; s <<= 1) {
                #pragma unroll
                for (int r = 0; r < 8; r += 2 * s) {
                    bool c = tv[r + s] > tv[r];
                    tv[r] = c ? tv[r + s] : tv[r];
                    ti[r] = c ? ti[r + s] : ti[r];
                    th[r] = c ? th[r + s] : th[r];
                }
            }
            float bv = tv[0];
            int   bi = (ti[0] << 6) | lane;
            float hb = th[0];

            // wave max; single-tie fast path avoids the 6-stage min reduce
            float maxv = wave_max_bcast_f32(bv);
            unsigned long long tie = __ballot(bv == maxv);
            int idx; float hwin;
            if (__popcll(tie) == 1) {
                int sl = __ffsll((unsigned long long)tie) - 1;     // uniform
                idx  = __builtin_amdgcn_readlane(bi, sl);
                hwin = __int_as_float(__builtin_amdgcn_readlane(__float_as_int(hb), sl));
            } else {
                // exact first-index tie-break (reference semantics)
                unsigned cand = (bv == maxv) ? (unsigned)bi : 0xffffffffu;
                idx = (int)wave_min_bcast_u32(cand);
                unsigned long long sm = __ballot((bv == maxv) && (bi == idx) && (hb < 0.f));
                hwin = (sm != 0ull) ? -maxv : maxv;
            }

            if ((idx & 63) == lane) msk |= 1u << (idx >> 6);
            Iv[k] = idx;
            const int rsel = idx >> 6, lsel = idx & 63;

            // prefetch new G row (coalesced; consumed by the u-update below)
            const float* grow = G + idx * KAT;
            float gk[8];
            if (k < 7) {
                #pragma unroll
                for (int r = 0; r < 8; ++r) gk[r] = grow[(r << 6) + lane];
            }

            // Cholesky row via identity L[k][i] = u_i[idx_k]: flat extraction
            // from uv registers (8 cndmask + readlane each), no loads, no chain.
            float Lk[7];
            if (k == 0) {
                invd[0] = 1.f;
            } else {
                float s2 = 0.f;
                #pragma unroll
                for (int i = 0; i < 7; ++i) if (i < k) {
                    float wsel = uv[i*8 + 0];
                    #pragma unroll
                    for (int r = 1; r < 8; ++r)
                        wsel = (rsel == r) ? uv[i*8 + r] : wsel;
                    float w = __int_as_float(
                        __builtin_amdgcn_readlane(__float_as_int(wsel), lsel));
                    Lk[i] = w;
                    s2 = fmaf(w, w, s2);
                }
                #pragma unroll
                for (int j = 0; j < 7; ++j) if (j < k) Lr[k*(k-1)/2 + j] = Lk[j];
                invd[k] = 1.f / sqrtf(1.f - s2);
            }
            yv[k] = hwin * invd[k];

            // u_k and incremental h update (not needed after last pick)
            if (k < 7) {
                #pragma unroll
                for (int r = 0; r < 8; ++r) {
                    float a = gk[r];
                    #pragma unroll
                    for (int j = 0; j < 7; ++j) if (j < k) a = fmaf(-Lk[j], uv[j*8 + r], a);
                    a *= invd[k];
                    uv[k*8 + r] = a;
                    h[r] = fmaf(-yv[k], a, h[r]);
                }
            }
        }

        // single back solve: L^T xr = yv
        #pragma unroll
        for (int i = 7; i >= 0; --i) {
            float a = yv[i];
            #pragma unroll
            for (int j = 0; j < 8; ++j) if (j > i) a = fmaf(-Lr[j*(j-1)/2 + i], xr[j], a);
            xr[i] = a * invd[i];
        }

        // ---- outputs for this column ----
        #pragma unroll
        for (int j = 0; j < 8; ++j)
            if (lane == j) out[O_GAMMA + Iv[j] * NCOL + n] = xr[j];

        // recon (lane = d), through the output permutation
        float rec = 0.f;
        #pragma unroll
        for (int j = 0; j < 8; ++j)
            rec = fmaf(xr[j], DnT[Iv[j] * DIM + lane], rec);
        int L = lane * NCOL + n;
        int perm = (L >> 16) * 65536 + (L & 63) * 1024 + (((L >> 11) & 31) << 5) + ((L >> 6) & 31);
        out[O_RECON + perm] = rec;

        // squared-error partial (all-VALU DPP sum; result uniform)
        float xd = xcols[lane * CPB + col];
        float diff = rec - xd;
        wv_sq += wave_sum_bcast_f32(diff * diff);

        // softmax-entropy: 8 nnz + 504 zeros, parallel over lanes 0..7
        {
            float m = 0.f;
            #pragma unroll
            for (int j = 0; j < 8; ++j) m = fmaxf(m, xr[j]);
            float xsel = 0.f;
            #pragma unroll
            for (int j = 0; j < 8; ++j) xsel = (lane == j) ? xr[j] : xsel;
            float e = (lane < 8) ? expf(xsel - m) : 0.f;
            float se = sum8_all_f32(e);          // valid on lanes 0..7
            float e0 = expf(-m);
            float Z = fmaf(504.f, e0, se);
            float invZ = 1.f / Z;
            float p = e * invZ;
            float tq = (lane < 8) ? p * logf(p + 1e-10f) : 0.f;
            tq = sum8_all_f32(tq);
            if (lane == 0) {
                float p0 = e0 * invZ;
                wv_S += tq + 504.f * p0 * logf(p0 + 1e-10f);
            }
        }
    }

    if (lane == 0) {
        atomicAdd(&acc[0], wv_sq);
        atomicAdd(&acc[1], wv_S);
    }
}

// ---------------------------------------------------------------------------
// Kernel 4: finalize scalars.
__global__ void fin_kernel(const float* __restrict__ ws, const float* __restrict__ beta,
                           float* __restrict__ out) {
    const float* acc = ws + WS_ACC;
    float mse = acc[0] / 2097152.f;                 // mean over 64*32768
    out[O_LOSS] = mse * 0.25f + beta[0] * mse;      // e_latent*cost + beta*q
    out[O_PERP] = expf(-acc[1] / 32768.f);
}

// ---------------------------------------------------------------------------
extern "C" void kernel_launch(void* const* d_in, const int* in_sizes, int n_in,
                              void* d_out, int out_size, void* d_ws, size_t ws_size,
                              hipStream_t stream) {
    const float* z_e  = (const float*)d_in[0];
    const float* dict = (const float*)d_in[1];
    const float* beta = (const float*)d_in[2];
    float* out = (float*)d_out;
    float* ws  = (float*)d_ws;

    zgp_kernel<<<9218, 256, 0, stream>>>(z_e, dict, out, ws);
    gram_kernel<<<512, 512, 0, stream>>>(ws, ws);
    omp_kernel<<<2048, 256, 0, stream>>>(z_e, ws, out, ws);
    fin_kernel<<<1, 1, 0, stream>>>(ws, beta, out);
}

// Round 5
// 364.486 us; speedup vs baseline: 1.1030x; 1.1030x over previous
//
#include <hip/hip_runtime.h>
#include <math.h>

// Problem constants
#define NCOL 32768          // N = 32*32*32 columns
#define KAT  512            // dictionary atoms
#define DIM  64             // embedding dim
#define CPB  16             // columns per omp block (LDS 36 KB -> 4 blocks/CU)

// Output flat offsets (fp32 elements)
#define O_LOSS  0
#define O_RECON 1
#define O_ZF    2097153     // 1 + 2097152
#define O_PERP  4194305
#define O_GAMMA 4194306

// Workspace layout (fp32 elements)
#define WS_DN   0           // Dn  [64][512]
#define WS_DNT  32768       // DnT [512][64]
#define WS_G    65536       // G   [512][512]
#define WS_ACC  327680      // acc[0]=sum((recon-zf)^2), acc[1]=sum_n S_n

// ---------------------------------------------------------------------------
// DPP wave-64 reductions (all-VALU; result broadcast via readlane)
__device__ __forceinline__ float wave_max_bcast_f32(float v) {
    int x = __float_as_int(v);
    int t;
    t = __builtin_amdgcn_update_dpp(x, x, 0x111, 0xf, 0xf, false);  // row_shr:1
    x = __float_as_int(fmaxf(__int_as_float(x), __int_as_float(t)));
    t = __builtin_amdgcn_update_dpp(x, x, 0x112, 0xf, 0xf, false);  // row_shr:2
    x = __float_as_int(fmaxf(__int_as_float(x), __int_as_float(t)));
    t = __builtin_amdgcn_update_dpp(x, x, 0x114, 0xf, 0xf, false);  // row_shr:4
    x = __float_as_int(fmaxf(__int_as_float(x), __int_as_float(t)));
    t = __builtin_amdgcn_update_dpp(x, x, 0x118, 0xf, 0xf, false);  // row_shr:8
    x = __float_as_int(fmaxf(__int_as_float(x), __int_as_float(t)));
    t = __builtin_amdgcn_update_dpp(x, x, 0x142, 0xa, 0xf, false);  // row_bcast:15
    x = __float_as_int(fmaxf(__int_as_float(x), __int_as_float(t)));
    t = __builtin_amdgcn_update_dpp(x, x, 0x143, 0xc, 0xf, false);  // row_bcast:31
    x = __float_as_int(fmaxf(__int_as_float(x), __int_as_float(t)));
    return __int_as_float(__builtin_amdgcn_readlane(x, 63));
}

__device__ __forceinline__ unsigned wave_min_bcast_u32(unsigned v) {
    int x = (int)v;
    int t;
    t = __builtin_amdgcn_update_dpp(x, x, 0x111, 0xf, 0xf, false);
    x = (int)min((unsigned)x, (unsigned)t);
    t = __builtin_amdgcn_update_dpp(x, x, 0x112, 0xf, 0xf, false);
    x = (int)min((unsigned)x, (unsigned)t);
    t = __builtin_amdgcn_update_dpp(x, x, 0x114, 0xf, 0xf, false);
    x = (int)min((unsigned)x, (unsigned)t);
    t = __builtin_amdgcn_update_dpp(x, x, 0x118, 0xf, 0xf, false);
    x = (int)min((unsigned)x, (unsigned)t);
    t = __builtin_amdgcn_update_dpp(x, x, 0x142, 0xa, 0xf, false);
    x = (int)min((unsigned)x, (unsigned)t);
    t = __builtin_amdgcn_update_dpp(x, x, 0x143, 0xc, 0xf, false);
    x = (int)min((unsigned)x, (unsigned)t);
    return (unsigned)__builtin_amdgcn_readlane(x, 63);
}

// Full-wave sum, result broadcast via readlane.
__device__ __forceinline__ float wave_sum_bcast_f32(float v) {
    int x = __float_as_int(v);
    int t;
    t = __builtin_amdgcn_update_dpp(x, x, 0x0B1, 0xf, 0xf, false);  // quad_perm [1,0,3,2]
    x = __float_as_int(__int_as_float(x) + __int_as_float(t));
    t = __builtin_amdgcn_update_dpp(x, x, 0x04E, 0xf, 0xf, false);  // quad_perm [2,3,0,1]
    x = __float_as_int(__int_as_float(x) + __int_as_float(t));
    t = __builtin_amdgcn_update_dpp(x, x, 0x141, 0xf, 0xf, false);  // row_half_mirror
    x = __float_as_int(__int_as_float(x) + __int_as_float(t));
    t = __builtin_amdgcn_update_dpp(x, x, 0x140, 0xf, 0xf, false);  // row_mirror
    x = __float_as_int(__int_as_float(x) + __int_as_float(t));
    t = __builtin_amdgcn_update_dpp(x, x, 0x142, 0xa, 0xf, false);  // row_bcast:15
    x = __float_as_int(__int_as_float(x) + __int_as_float(t));
    t = __builtin_amdgcn_update_dpp(x, x, 0x143, 0xc, 0xf, false);  // row_bcast:31
    x = __float_as_int(__int_as_float(x) + __int_as_float(t));
    return __int_as_float(__builtin_amdgcn_readlane(x, 63));
}

// Sum over each 8-lane group, result on ALL lanes of the group (3 DPP stages).
__device__ __forceinline__ float sum8_all_f32(float v) {
    int x = __float_as_int(v);
    int t;
    t = __builtin_amdgcn_update_dpp(x, x, 0x0B1, 0xf, 0xf, false);  // xor1
    x = __float_as_int(__int_as_float(x) + __int_as_float(t));
    t = __builtin_amdgcn_update_dpp(x, x, 0x04E, 0xf, 0xf, false);  // xor2
    x = __float_as_int(__int_as_float(x) + __int_as_float(t));
    t = __builtin_amdgcn_update_dpp(x, x, 0x141, 0xf, 0xf, false);  // xor4 (half_mirror)
    x = __float_as_int(__int_as_float(x) + __int_as_float(t));
    return __int_as_float(x);
}

// ---------------------------------------------------------------------------
// Kernel 1: merged zf permutation-gather (blocks 0..1023) + gamma zero-fill
// (blocks 1024..9215) + dictionary prep (blocks 9216..9217).
__global__ __launch_bounds__(256) void zgp_kernel(const float* __restrict__ z_e,
                                                  const float* __restrict__ dict,
                                                  float* __restrict__ out,
                                                  float* __restrict__ ws) {
    __shared__ float tile[64 * 33];   // [c][w], pad to 33 -> conflict-free
    int t = threadIdx.x;
    if (blockIdx.x < 1024) {
        int s = blockIdx.x;           // one (b,h) slab each
        int b = s >> 5, h = s & 31;
        int srcbase = b * 65536 + h * 32;
        #pragma unroll
        for (int i = 0; i < 8; ++i) {
            int e = t + i * 256;      // e = c*32 + w
            int c = e >> 5, w = e & 31;
            tile[c * 33 + w] = z_e[srcbase + c * 1024 + w];
        }
        __syncthreads();
        int obase = O_ZF + s * 2048;
        #pragma unroll
        for (int i = 0; i < 8; ++i) {
            int e = t + i * 256;      // e = w*64 + c
            out[obase + e] = tile[(e & 63) * 33 + (e >> 6)];
        }
    } else if (blockIdx.x < 9216) {
        float2* g2 = (float2*)(out + O_GAMMA);   // region only 8B-aligned
        int id = (blockIdx.x - 1024) * 256 + t;  // 8192 blocks' worth
        #pragma unroll
        for (int i = 0; i < 4; ++i)
            g2[id + i * 2097152] = make_float2(0.f, 0.f);
    } else {
        // dictionary prep: normalize columns -> Dn, DnT; zero accumulators
        float* Dn  = ws + WS_DN;
        float* DnT = ws + WS_DNT;
        float* acc = ws + WS_ACC;
        int a = (blockIdx.x - 9216) * 256 + t;   // 0..511
        if (blockIdx.x == 9216 && t < 2) acc[t] = 0.f;
        float s = 0.f;
        #pragma unroll
        for (int d = 0; d < DIM; ++d) { float v = dict[d*KAT + a]; s += v * v; }
        float nrm = sqrtf(s);
        #pragma unroll
        for (int d = 0; d < DIM; ++d) {
            float v = dict[d*KAT + a] / nrm;
            Dn[d*KAT + a]  = v;
            DnT[a*DIM + d] = v;
        }
    }
}

// ---------------------------------------------------------------------------
// Kernel 2: G = Dn^T Dn.  block = row i (512 blocks), thread = col j (512).
// NOTE: G must be bit-symmetric (the omp kernel's Cholesky identity relies on
// it): fmaf(Dn_i, Dn_j, s) with operand swap is bit-identical, so it is.
__global__ void gram_kernel(const float* __restrict__ ws_in, float* __restrict__ ws) {
    const float* Dn = ws_in + WS_DN;
    float* G = ws + WS_G;
    int i = blockIdx.x, j = threadIdx.x;
    float s = 0.f;
    #pragma unroll
    for (int d = 0; d < DIM; ++d)
        s = fmaf(Dn[d*KAT + i], Dn[d*KAT + j], s);
    G[i*KAT + j] = s;
}

// ---------------------------------------------------------------------------
// Kernel 3: fused h_bar + Batch-OMP. 16 columns per 256-thread block; one wave
// per column, 4 columns/wave. This is the round-3 kernel (measured 256.6 us)
// with EXACTLY ONE change: the per-pick Cholesky extension (7 uniform G loads
// at ~200cy + 28-deep dependent FMA chain) is replaced by the exact Batch-OMP
// identity  L[k][i] = u_i[idx_k]  — extracted from the uv[] registers with
// 7 cndmasks + 1 readlane per entry (flat ops, no memory, no chain).
// Proof: w = L^{-1} g, g[i] = G[Iv[i]][idx_k]; u_i = row i of L^{-1} G_I.
// Bit-exact by induction (identical fmaf sequence; G bit-symmetric).
// The round-4 tree-argmax is NOT reapplied: its 24 extra live temporaries
// pushed past the ~128-reg/wave budget at 4 waves/SIMD and caused massive
// scratch+LDS spills (WRITE_SIZE 31->245 MB, LDS +4KB).
__global__ __launch_bounds__(256, 4) void omp_kernel(const float* __restrict__ z_e,
                                                     const float* __restrict__ ws,
                                                     float* __restrict__ out,
                                                     float* __restrict__ wsw) {
    const float* Dn  = ws + WS_DN;
    const float* DnT = ws + WS_DNT;
    const float* G   = ws + WS_G;
    float* acc = wsw + WS_ACC;

    __shared__ __align__(16) float xcols[DIM * CPB];  // [d][c]   4 KB
    __shared__ float hbar[CPB * KAT];                 // [c][a]  32 KB

    const int t = threadIdx.x;
    const int n_base = blockIdx.x * CPB;

    // ---- Phase 1: gather data columns
    #pragma unroll
    for (int i = 0; i < 4; ++i) {
        int e = t + i * 256;              // 0..1023, e = d*16 + c
        int d = e >> 4, c = e & 15;
        int L = d * NCOL + n_base + c;
        int src = (L >> 16) * 65536 + (L & 63) * 1024 + (((L >> 11) & 31) << 5) + ((L >> 6) & 31);
        xcols[e] = z_e[src];
    }
    __syncthreads();

    // ---- Phase 2: h_bar tile (Dn read once per block)
    {
        float a0[16], a1[16];
        #pragma unroll
        for (int i = 0; i < 16; ++i) { a0[i] = 0.f; a1[i] = 0.f; }
        const float4* xc4 = (const float4*)xcols;
        for (int d = 0; d < DIM; ++d) {
            float v0 = Dn[d * KAT + t];
            float v1 = Dn[d * KAT + 256 + t];
            #pragma unroll
            for (int q = 0; q < 4; ++q) {
                float4 xv = xc4[d * 4 + q];
                a0[q*4+0] = fmaf(v0, xv.x, a0[q*4+0]);
                a0[q*4+1] = fmaf(v0, xv.y, a0[q*4+1]);
                a0[q*4+2] = fmaf(v0, xv.z, a0[q*4+2]);
                a0[q*4+3] = fmaf(v0, xv.w, a0[q*4+3]);
                a1[q*4+0] = fmaf(v1, xv.x, a1[q*4+0]);
                a1[q*4+1] = fmaf(v1, xv.y, a1[q*4+1]);
                a1[q*4+2] = fmaf(v1, xv.z, a1[q*4+2]);
                a1[q*4+3] = fmaf(v1, xv.w, a1[q*4+3]);
            }
        }
        #pragma unroll
        for (int c = 0; c < 16; ++c) {
            hbar[c * KAT + t]       = a0[c];
            hbar[c * KAT + 256 + t] = a1[c];
        }
    }
    __syncthreads();

    // ---- Phase 3: OMP, one wave per column, 4 columns sequentially
    const int wv = t >> 6, lane = t & 63;
    float wv_sq = 0.f, wv_S = 0.f;

    #pragma unroll 1
    for (int cc = 0; cc < 4; ++cc) {
        const int col = wv * 4 + cc;
        const int n = n_base + col;
        const float* hbcol = hbar + col * KAT;

        float h[8];
        #pragma unroll
        for (int r = 0; r < 8; ++r) h[r] = hbcol[(r << 6) + lane];

        unsigned msk = 0;
        float uv[56];                 // u_0..u_6, uv[j*8+r]
        float Lr[28];                 // off-diag rows 1..7: Lr[i*(i-1)/2+j], j<i
        float invd[8], yv[8], xr[8];
        int Iv[8];

        #pragma unroll
        for (int k = 0; k < 8; ++k) {
            // local argmax over this lane's 8 slots (track signed winner)
            float bv = -1.f; int bi = 0; float hb = 0.f;
            #pragma unroll
            for (int r = 0; r < 8; ++r) {
                float av = ((msk >> r) & 1) ? -1.f : fabsf(h[r]);
                bool gt = av > bv;
                bv = gt ? av : bv;
                bi = gt ? ((r << 6) | lane) : bi;
                hb = gt ? h[r] : hb;
            }
            // wave max; single-tie fast path avoids the 6-stage min reduce
            float maxv = wave_max_bcast_f32(bv);
            unsigned long long tie = __ballot(bv == maxv);
            int idx; float hwin;
            if (__popcll(tie) == 1) {
                int sl = __ffsll((unsigned long long)tie) - 1;     // uniform
                idx  = __builtin_amdgcn_readlane(bi, sl);
                hwin = __int_as_float(__builtin_amdgcn_readlane(__float_as_int(hb), sl));
            } else {
                // exact first-index tie-break (reference semantics)
                unsigned cand = (bv == maxv) ? (unsigned)bi : 0xffffffffu;
                idx = (int)wave_min_bcast_u32(cand);
                unsigned long long sm = __ballot((bv == maxv) && (bi == idx) && (hb < 0.f));
                hwin = (sm != 0ull) ? -maxv : maxv;
            }

            if ((idx & 63) == lane) msk |= 1u << (idx >> 6);
            Iv[k] = idx;
            const int rsel = idx >> 6, lsel = idx & 63;

            // prefetch new G row (coalesced; consumed by the u-update below).
            // Last pick (k==7) issues no memory ops at all.
            const float* grow = G + idx * KAT;
            float gk[8];
            if (k < 7) {
                #pragma unroll
                for (int r = 0; r < 8; ++r) gk[r] = grow[(r << 6) + lane];
            }

            // Cholesky row via identity L[k][i] = u_i[idx_k]: flat extraction
            // from uv registers (7 cndmask + 1 readlane each), no loads, no chain.
            float Lk[7];
            if (k == 0) {
                invd[0] = 1.f;
            } else {
                float s2 = 0.f;
                #pragma unroll
                for (int i = 0; i < 7; ++i) if (i < k) {
                    float wsel = uv[i*8 + 0];
                    #pragma unroll
                    for (int r = 1; r < 8; ++r)
                        wsel = (rsel == r) ? uv[i*8 + r] : wsel;
                    float w = __int_as_float(
                        __builtin_amdgcn_readlane(__float_as_int(wsel), lsel));
                    Lk[i] = w;
                    s2 = fmaf(w, w, s2);
                }
                #pragma unroll
                for (int j = 0; j < 7; ++j) if (j < k) Lr[k*(k-1)/2 + j] = Lk[j];
                invd[k] = 1.f / sqrtf(1.f - s2);
            }
            yv[k] = hwin * invd[k];

            // u_k and incremental h update (not needed after last pick)
            if (k < 7) {
                #pragma unroll
                for (int r = 0; r < 8; ++r) {
                    float a = gk[r];
                    #pragma unroll
                    for (int j = 0; j < 7; ++j) if (j < k) a = fmaf(-Lk[j], uv[j*8 + r], a);
                    a *= invd[k];
                    uv[k*8 + r] = a;
                    h[r] = fmaf(-yv[k], a, h[r]);
                }
            }
        }

        // single back solve: L^T xr = yv
        #pragma unroll
        for (int i = 7; i >= 0; --i) {
            float a = yv[i];
            #pragma unroll
            for (int j = 0; j < 8; ++j) if (j > i) a = fmaf(-Lr[j*(j-1)/2 + i], xr[j], a);
            xr[i] = a * invd[i];
        }

        // ---- outputs for this column ----
        #pragma unroll
        for (int j = 0; j < 8; ++j)
            if (lane == j) out[O_GAMMA + Iv[j] * NCOL + n] = xr[j];

        // recon (lane = d), through the output permutation
        float rec = 0.f;
        #pragma unroll
        for (int j = 0; j < 8; ++j)
            rec = fmaf(xr[j], DnT[Iv[j] * DIM + lane], rec);
        int L = lane * NCOL + n;
        int perm = (L >> 16) * 65536 + (L & 63) * 1024 + (((L >> 11) & 31) << 5) + ((L >> 6) & 31);
        out[O_RECON + perm] = rec;

        // squared-error partial (all-VALU DPP sum; result uniform)
        float xd = xcols[lane * CPB + col];
        float diff = rec - xd;
        wv_sq += wave_sum_bcast_f32(diff * diff);

        // softmax-entropy: 8 nnz + 504 zeros, parallel over lanes 0..7
        {
            float m = 0.f;
            #pragma unroll
            for (int j = 0; j < 8; ++j) m = fmaxf(m, xr[j]);
            float xsel = 0.f;
            #pragma unroll
            for (int j = 0; j < 8; ++j) xsel = (lane == j) ? xr[j] : xsel;
            float e = (lane < 8) ? expf(xsel - m) : 0.f;
            float se = sum8_all_f32(e);          // valid on lanes 0..7
            float e0 = expf(-m);
            float Z = fmaf(504.f, e0, se);
            float invZ = 1.f / Z;
            float p = e * invZ;
            float tq = (lane < 8) ? p * logf(p + 1e-10f) : 0.f;
            tq = sum8_all_f32(tq);
            if (lane == 0) {
                float p0 = e0 * invZ;
                wv_S += tq + 504.f * p0 * logf(p0 + 1e-10f);
            }
        }
    }

    if (lane == 0) {
        atomicAdd(&acc[0], wv_sq);
        atomicAdd(&acc[1], wv_S);
    }
}

// ---------------------------------------------------------------------------
// Kernel 4: finalize scalars.
__global__ void fin_kernel(const float* __restrict__ ws, const float* __restrict__ beta,
                           float* __restrict__ out) {
    const float* acc = ws + WS_ACC;
    float mse = acc[0] / 2097152.f;                 // mean over 64*32768
    out[O_LOSS] = mse * 0.25f + beta[0] * mse;      // e_latent*cost + beta*q
    out[O_PERP] = expf(-acc[1] / 32768.f);
}

// ---------------------------------------------------------------------------
extern "C" void kernel_launch(void* const* d_in, const int* in_sizes, int n_in,
                              void* d_out, int out_size, void* d_ws, size_t ws_size,
                              hipStream_t stream) {
    const float* z_e  = (const float*)d_in[0];
    const float* dict = (const float*)d_in[1];
    const float* beta = (const float*)d_in[2];
    float* out = (float*)d_out;
    float* ws  = (float*)d_ws;

    zgp_kernel<<<9218, 256, 0, stream>>>(z_e, dict, out, ws);
    gram_kernel<<<512, 512, 0, stream>>>(ws, ws);
    omp_kernel<<<2048, 256, 0, stream>>>(z_e, ws, out, ws);
    fin_kernel<<<1, 1, 0, stream>>>(ws, beta, out);
}